// Round 4
// baseline (470.672 us; speedup 1.0000x reference)
//
#include <hip/hip_runtime.h>

// Problem: B=1, L=768, D_SINGLE=384, D_PAIR=128
//   left  = s @ W[:384]    (768 x 128)
//   right = s @ W[384:]    (768 x 128)
//   out[i,j,f] = left[i,f] + right[j,f] + bias[f]   -> (1,768,768,128) fp32
// z (d_in[1]) is UNUSED by the reference.

#define L_DIM   768
#define D_S     384
#define D_P     128

// ---------------- Kernel A: projection -------------------------------------
// grid = (192), block = (256). Block b handles rows 4b..4b+3.
// threadIdx.x = f in [0,256): f<128 -> left column fc=f (bias folded),
// f>=128 -> right column fc=f-128. Each thread streams one W column once
// (the per-block W stream from L2 is the floor, ~3 us) and applies it to
// 4 rows. s rows broadcast from LDS (same-address -> conflict-free).
__global__ __launch_bounds__(256) void proj_kernel(
    const float* __restrict__ s,     // (768, 384)
    const float* __restrict__ W,     // (768, 128)
    const float* __restrict__ bias,  // (128,)
    float* __restrict__ proj)        // (768, 256)
{
    __shared__ float s_rows[4][D_S];   // 6 KB
    const int l0 = blockIdx.x * 4;
    const int f  = threadIdx.x;

    for (int d = threadIdx.x; d < 4 * D_S; d += 256)
        s_rows[0][d] = s[l0 * D_S + d];   // [4][D_S] contiguous, coalesced
    __syncthreads();

    const int fc = f & (D_P - 1);
    const float* Wbase = W + ((f >= D_P) ? (D_S * D_P) : 0) + fc;

    const float binit = (f < D_P) ? bias[fc] : 0.0f;  // bias folded into left
    float a0 = binit, a1 = binit, a2 = binit, a3 = binit;
#pragma unroll 4
    for (int d = 0; d < D_S; ++d) {
        const float w = Wbase[(size_t)d * D_P];
        a0 = fmaf(s_rows[0][d], w, a0);
        a1 = fmaf(s_rows[1][d], w, a1);
        a2 = fmaf(s_rows[2][d], w, a2);
        a3 = fmaf(s_rows[3][d], w, a3);
    }
    proj[(size_t)(l0 + 0) * 256 + f] = a0;
    proj[(size_t)(l0 + 1) * 256 + f] = a1;
    proj[(size_t)(l0 + 2) * 256 + f] = a2;
    proj[(size_t)(l0 + 3) * 256 + f] = a3;
}

// ---------------- Kernel B: outer broadcast sum ----------------------------
// Same indexing/coalescing as the proven round-0 kernel (plain stores,
// each wave stores one contiguous 1 KB segment per iteration), but each
// block now loops ITERS=12 times -> 6144 blocks instead of 73728, so
// block launch/drain overhead amortizes like the 6.5 TB/s fill kernel.
// lv (left row) is register-resident across the whole loop (i, f4 fixed).
#define XBLK  8
#define ITERS (L_DIM * (D_P / 4) / (XBLK * 256))   // 12
__global__ __launch_bounds__(256) void outer_kernel(
    const float4* __restrict__ proj4,  // (768, 64) float4 view of proj
    float4* __restrict__ out4)         // (768*768*32) float4
{
    const int i   = blockIdx.y;
    const int tid = threadIdx.x;
    const int f4  = tid & 31;
    const int t0  = blockIdx.x * (ITERS * 256) + tid;

    const float4 lv = proj4[i * 64 + f4];   // loaded once per thread
    float4* ob = out4 + (size_t)i * (L_DIM * (D_P / 4)) + t0;

#pragma unroll
    for (int k = 0; k < ITERS; ++k) {
        const int j = (t0 + k * 256) >> 5;          // f4 invariant in k
        const float4 rv = proj4[(size_t)j * 64 + 32 + f4];
        float4 o;
        o.x = lv.x + rv.x;
        o.y = lv.y + rv.y;
        o.z = lv.z + rv.z;
        o.w = lv.w + rv.w;
        ob[k * 256] = o;                             // contiguous 1 KB/wave
    }
}

extern "C" void kernel_launch(void* const* d_in, const int* in_sizes, int n_in,
                              void* d_out, int out_size, void* d_ws, size_t ws_size,
                              hipStream_t stream) {
    const float* s    = (const float*)d_in[0];
    // d_in[1] = z, unused by the reference
    const float* W    = (const float*)d_in[2];
    const float* bias = (const float*)d_in[3];
    float* out  = (float*)d_out;
    float* proj = (float*)d_ws;   // 768*256 floats = 786 KB

    proj_kernel<<<dim3(L_DIM / 4), dim3(256), 0, stream>>>(s, W, bias, proj);

    outer_kernel<<<dim3(XBLK, L_DIM), dim3(256), 0, stream>>>(
        (const float4*)proj, (float4*)out);
}

// Round 5
// 439.475 us; speedup vs baseline: 1.0710x; 1.0710x over previous
//
#include <hip/hip_runtime.h>

// Problem: B=1, L=768, D_SINGLE=384, D_PAIR=128
//   left  = s @ W[:384]    (768 x 128)
//   right = s @ W[384:]    (768 x 128)
//   out[i,j,f] = left[i,f] + right[j,f] + bias[f]   -> (1,768,768,128) fp32
// z (d_in[1]) is UNUSED by the reference.
//
// MEASURED HISTORY (do not "improve" outer_kernel again without new evidence):
//   r0  (1-row proj, this outer):            440.7 us
//   r2  (nontemporal + strided outer):       450.9 us  <- nt stores hurt
//   r3  (THIS SOURCE):                       440.2 us  <- best
//   r4  (12-iter coarsened outer):           470.7 us  <- TLP loss hurt
// dur_us is dominated by 2x ~186 us harness fills; outer (~52 us) sits at
// ~90% of the 302 MB write floor at the measured-achievable 6.5 TB/s.

#define L_DIM   768
#define D_S     384
#define D_P     128

// ---------------- Kernel A: projection -------------------------------------
// grid = (384), block = (256). Block b handles rows 2b, 2b+1.
// threadIdx.x = f in [0,256): f<128 -> left column fc=f (bias folded),
// f>=128 -> right column fc=f-128. Each thread streams one W column once
// and applies it to BOTH rows. Per-block W stream from L2 (~393 KB) is the
// floor; aggregate-traffic reduction beyond 2 rows measured as neutral.
__global__ __launch_bounds__(256) void proj_kernel(
    const float* __restrict__ s,     // (768, 384)
    const float* __restrict__ W,     // (768, 128)
    const float* __restrict__ bias,  // (128,)
    float* __restrict__ proj)        // (768, 256)
{
    __shared__ float s_rows[2][D_S];
    const int l0 = blockIdx.x * 2;
    const int f  = threadIdx.x;

    // stage 2 s rows (3 KB) into LDS, coalesced
    for (int d = threadIdx.x; d < 2 * D_S; d += 256)
        s_rows[0][d] = s[l0 * D_S + d];   // [2][D_S] is contiguous
    __syncthreads();

    const int fc = f & (D_P - 1);
    const float* Wbase = W + ((f >= D_P) ? (D_S * D_P) : 0) + fc;

    const float binit = (f < D_P) ? bias[fc] : 0.0f;  // bias folded into left
    float acc0 = binit;
    float acc1 = binit;
#pragma unroll 8
    for (int d = 0; d < D_S; ++d) {
        const float w = Wbase[(size_t)d * D_P];
        acc0 = fmaf(s_rows[0][d], w, acc0);
        acc1 = fmaf(s_rows[1][d], w, acc1);
    }
    proj[(size_t)l0 * 256 + f]       = acc0;
    proj[(size_t)(l0 + 1) * 256 + f] = acc1;
}

// ---------------- Kernel B: outer broadcast sum ----------------------------
// PROVEN structure (440.2 us total). grid = (96, 768), block = 256.
// blockIdx.y = i. t = blockIdx.x*256 + tid: f4 = t & 31, j = t >> 5.
// One float4 store per thread, each wave = one contiguous 1 KB segment;
// 73728 tiny blocks maximize store-stream TLP (coarsening regressed, r4;
// nontemporal stores regressed, r2).
__global__ __launch_bounds__(256) void outer_kernel(
    const float4* __restrict__ proj4,  // (768, 64) float4 view of proj
    float4* __restrict__ out4)         // (768*768*32) float4
{
    const int i  = blockIdx.y;
    const int t  = blockIdx.x * 256 + threadIdx.x;  // [0, 24576)
    const int f4 = t & 31;
    const int j  = t >> 5;

    const float4 lv = proj4[i * 64 + f4];        // left row, L1-broadcast
    const float4 rv = proj4[j * 64 + 32 + f4];   // right row

    float4 o;
    o.x = lv.x + rv.x;
    o.y = lv.y + rv.y;
    o.z = lv.z + rv.z;
    o.w = lv.w + rv.w;

    out4[(size_t)i * (L_DIM * (D_P / 4)) + t] = o;
}

extern "C" void kernel_launch(void* const* d_in, const int* in_sizes, int n_in,
                              void* d_out, int out_size, void* d_ws, size_t ws_size,
                              hipStream_t stream) {
    const float* s    = (const float*)d_in[0];
    // d_in[1] = z, unused by the reference
    const float* W    = (const float*)d_in[2];
    const float* bias = (const float*)d_in[3];
    float* out  = (float*)d_out;
    float* proj = (float*)d_ws;   // 768*256 floats = 786 KB

    proj_kernel<<<dim3(L_DIM / 2), dim3(256), 0, stream>>>(s, W, bias, proj);

    outer_kernel<<<dim3(L_DIM * (D_P / 4) / 256, L_DIM), dim3(256), 0, stream>>>(
        (const float4*)proj, (float4*)out);
}